// Round 17
// baseline (74.930 us; speedup 1.0000x reference)
//
#include <hip/hip_runtime.h>
#include <hip/hip_bf16.h>
#include <math.h>

// GAT forward, N=4096, F=512, H=8, NH=64.
// Round 17: adj extraction fused into gemm1 with parity anti-alignment
// (even blocks: gemm->scan8rows; odd: scan8rows->gemm) so the HBM-bound
// 64MB scan overlaps the MFMA-bound gemm across co-resident blocks.
// attn8 loses the scan (reads nbrs). Else = r16.

#define GN 4096
#define GF 512
#define CAP2 256
#define PS2 260

typedef __attribute__((ext_vector_type(8))) short bf16x8;
typedef __attribute__((ext_vector_type(4))) float f32x4;
typedef __attribute__((ext_vector_type(4))) _Float16 f16x4;

__device__ inline unsigned short f2bf(float f) {
    unsigned u = __float_as_uint(f);
    return (unsigned short)((u + 0x7fffu + ((u >> 16) & 1u)) >> 16);
}
__device__ inline float bf2f(unsigned short h) {
    return __uint_as_float((unsigned)h << 16);
}
__device__ inline void split2(float v, unsigned short& h, unsigned short& l) {
    h = f2bf(v);
    l = f2bf(v - bf2f(h));
}
__device__ inline void gl16(const void* g, void* l) {
    __builtin_amdgcn_global_load_lds((const __attribute__((address_space(1))) unsigned int*)g,
                                     (__attribute__((address_space(3))) unsigned int*)l, 16, 0, 0);
}

// ---- prep: LDS-transposed packs of Ws/Wo + split x. grid = 64+64+2048 ----
__global__ __launch_bounds__(256) void prep(
        const float* __restrict__ Ws, const float* __restrict__ Wo,
        const float* __restrict__ x,
        unsigned short* __restrict__ wshi, unsigned short* __restrict__ wslo,
        unsigned short* __restrict__ wohi, unsigned short* __restrict__ wolo,
        unsigned short* __restrict__ xhi, unsigned short* __restrict__ xlo) {
    __shared__ float T[64][65];
    int b = blockIdx.x;
    const int t = threadIdx.x;
    if (b < 64) {                         // Ws[h][f][k] -> Bt[h*64+k][f], tiled
        const int h = b >> 3, f0 = (b & 7) * 64;
        #pragma unroll
        for (int i = 0; i < 16; ++i) {
            int idx = i * 256 + t;
            int fr = idx >> 6, k = idx & 63;
            T[fr][k] = Ws[h * 32768 + (f0 + fr) * 64 + k];
        }
        __syncthreads();
        #pragma unroll
        for (int i = 0; i < 16; ++i) {
            int idx = i * 256 + t;
            int k = idx >> 6, fr = idx & 63;
            unsigned short hh, ll;
            split2(T[fr][k], hh, ll);
            size_t dst = (size_t)(h * 64 + k) * 512 + f0 + fr;
            wshi[dst] = hh; wslo[dst] = ll;
        }
        return;
    }
    b -= 64;
    if (b < 64) {                         // Wo[f][c] -> Bt[c][f], tiled
        const int c0 = (b >> 3) * 64, f0 = (b & 7) * 64;
        #pragma unroll
        for (int i = 0; i < 16; ++i) {
            int idx = i * 256 + t;
            int fr = idx >> 6, k = idx & 63;
            T[fr][k] = Wo[(size_t)(f0 + fr) * 512 + c0 + k];
        }
        __syncthreads();
        #pragma unroll
        for (int i = 0; i < 16; ++i) {
            int idx = i * 256 + t;
            int k = idx >> 6, fr = idx & 63;
            unsigned short hh, ll;
            split2(T[fr][k], hh, ll);
            size_t dst = (size_t)(c0 + k) * 512 + f0 + fr;
            wohi[dst] = hh; wolo[dst] = ll;
        }
        return;
    }
    b -= 64;
    {                                     // split x -> hi/lo, 2048 blocks
        int i = b * 256 + t;              // [0, 524288)
        float4 v = ((const float4*)x)[i];
        ushort4 h, l;
        split2(v.x, h.x, l.x); split2(v.y, h.y, l.y);
        split2(v.z, h.z, l.z); split2(v.w, h.w, l.w);
        ((ushort4*)xhi)[i] = h;
        ((ushort4*)xlo)[i] = l;
    }
}

// ---- MFMA GEMM (+ optional fused adj extraction): C(fp16) = A@B.
// 64x64 tile, BK=64, dbuf LDS, 3-term bf16 split, both-sides XOR swizzle,
// XCD swizzle. s/d epilogue -> [row][8]. SCAN: block also extracts 8 adj rows
// (rows blk*8..blk*8+7) with parity anti-alignment for HBM/MFMA overlap.
template<bool SCAN>
__global__ __launch_bounds__(256) void gemm_3t(
        const unsigned short* __restrict__ Ahi, const unsigned short* __restrict__ Alo,
        const unsigned short* __restrict__ Bhi, const unsigned short* __restrict__ Blo,
        const float* __restrict__ a1v, const float* __restrict__ a2v,
        _Float16* __restrict__ C, float* __restrict__ sdst, float* __restrict__ ddst,
        const float* __restrict__ adj, unsigned short* __restrict__ nbr,
        int* __restrict__ deg, int M, int K, int Nc) {
    __shared__ char lds[65536];           // 2 buffers x 32KB (Ah|Al|Bh|Bl)
    const int t = threadIdx.x, lane = t & 63, wid = t >> 6;
    const int blk = blockIdx.x;
    const int bmI = (blk & 7) | ((blk >> 6) << 3);   // 0..63
    const int bnI = (blk >> 3) & 7;                  // 0..7
    const int bm0 = bmI * 64, bn0 = bnI * 64;
    const int r0 = t >> 3;
    const int sc8 = (((t & 7) ^ ((t >> 3) & 7)) << 3);   // swizzled chunk, elems
    const size_t aoff = (size_t)(bm0 + r0) * K + sc8;
    const size_t boff = (size_t)(bn0 + r0) * K + sc8;
    const size_t half = (size_t)32 * K;

    auto scan8 = [&]() {                  // extract rows blk*8 .. blk*8+7
        int* wt = (int*)lds;              // 4 ints; phases barrier-separated
        #pragma unroll 1
        for (int r8 = 0; r8 < 8; ++r8) {
            const int row = blk * 8 + r8;
            const float4* arow = (const float4*)(adj + (size_t)row * 4096);
            unsigned m16 = 0;
            #pragma unroll
            for (int q = 0; q < 4; ++q) {
                float4 v = arow[q * 256 + t];  // coalesced
                if (v.x > 0.f) m16 |= 1u << (q * 4 + 0);
                if (v.y > 0.f) m16 |= 1u << (q * 4 + 1);
                if (v.z > 0.f) m16 |= 1u << (q * 4 + 2);
                if (v.w > 0.f) m16 |= 1u << (q * 4 + 3);
            }
            const int cnt = __popc(m16);
            int inc = cnt;
            #pragma unroll
            for (int off = 1; off < 64; off <<= 1) {
                int nv = __shfl_up(inc, off);
                if (lane >= off) inc += nv;
            }
            if (lane == 63) wt[wid] = inc;
            __syncthreads();
            int wb = 0;
            #pragma unroll
            for (int w = 0; w < 4; ++w) wb += (w < wid) ? wt[w] : 0;
            if (t == 0) deg[row] = wt[0] + wt[1] + wt[2] + wt[3];
            int base = wb + inc - cnt;
            unsigned m = m16;
            int k = 0;
            while (m) {
                int b = __ffs(m) - 1;
                m &= m - 1;
                int col = ((b >> 2) << 10) + t * 4 + (b & 3);
                nbr[(size_t)row * 512 + base + k] = (unsigned short)col;
                ++k;
            }
            __syncthreads();              // wt reuse next row
        }
    };

    f32x4 acc00 = {0,0,0,0}, acc01 = {0,0,0,0}, acc10 = {0,0,0,0}, acc11 = {0,0,0,0};
    const int mq = (wid >> 1) * 32, nq = (wid & 1) * 32;
    const int rl = lane & 15, hl = lane >> 4;
    const int swz = rl & 7;

    auto stage = [&](char* dst, int k0) {
        gl16(Ahi + aoff + k0,        dst + 0 * 4096 + t * 16);
        gl16(Ahi + aoff + half + k0, dst + 1 * 4096 + t * 16);
        gl16(Alo + aoff + k0,        dst + 2 * 4096 + t * 16);
        gl16(Alo + aoff + half + k0, dst + 3 * 4096 + t * 16);
        gl16(Bhi + boff + k0,        dst + 4 * 4096 + t * 16);
        gl16(Bhi + boff + half + k0, dst + 5 * 4096 + t * 16);
        gl16(Blo + boff + k0,        dst + 6 * 4096 + t * 16);
        gl16(Blo + boff + half + k0, dst + 7 * 4096 + t * 16);
    };

    auto compute = [&](const char* Lb) {
        const char* Ah_ = Lb;
        const char* Al_ = Lb + 8192;
        const char* Bh_ = Lb + 16384;
        const char* Bl_ = Lb + 24576;
        #pragma unroll
        for (int s = 0; s < 2; ++s) {
            const int ch = ((s * 4 + hl) ^ swz) * 16;
            const int ra0 = (mq + rl) * 128, ra1 = ra0 + 16 * 128;
            const int rb0 = (nq + rl) * 128, rb1 = rb0 + 16 * 128;
            bf16x8 A0h = *(const bf16x8*)(Ah_ + ra0 + ch);
            bf16x8 A1h = *(const bf16x8*)(Ah_ + ra1 + ch);
            bf16x8 A0l = *(const bf16x8*)(Al_ + ra0 + ch);
            bf16x8 A1l = *(const bf16x8*)(Al_ + ra1 + ch);
            bf16x8 B0h = *(const bf16x8*)(Bh_ + rb0 + ch);
            bf16x8 B1h = *(const bf16x8*)(Bh_ + rb1 + ch);
            bf16x8 B0l = *(const bf16x8*)(Bl_ + rb0 + ch);
            bf16x8 B1l = *(const bf16x8*)(Bl_ + rb1 + ch);
            acc00 = __builtin_amdgcn_mfma_f32_16x16x32_bf16(A0h, B0h, acc00, 0, 0, 0);
            acc01 = __builtin_amdgcn_mfma_f32_16x16x32_bf16(A0h, B1h, acc01, 0, 0, 0);
            acc10 = __builtin_amdgcn_mfma_f32_16x16x32_bf16(A1h, B0h, acc10, 0, 0, 0);
            acc11 = __builtin_amdgcn_mfma_f32_16x16x32_bf16(A1h, B1h, acc11, 0, 0, 0);
            acc00 = __builtin_amdgcn_mfma_f32_16x16x32_bf16(A0h, B0l, acc00, 0, 0, 0);
            acc01 = __builtin_amdgcn_mfma_f32_16x16x32_bf16(A0h, B1l, acc01, 0, 0, 0);
            acc10 = __builtin_amdgcn_mfma_f32_16x16x32_bf16(A1h, B0l, acc10, 0, 0, 0);
            acc11 = __builtin_amdgcn_mfma_f32_16x16x32_bf16(A1h, B1l, acc11, 0, 0, 0);
            acc00 = __builtin_amdgcn_mfma_f32_16x16x32_bf16(A0l, B0h, acc00, 0, 0, 0);
            acc01 = __builtin_amdgcn_mfma_f32_16x16x32_bf16(A0l, B1h, acc01, 0, 0, 0);
            acc10 = __builtin_amdgcn_mfma_f32_16x16x32_bf16(A1l, B0h, acc10, 0, 0, 0);
            acc11 = __builtin_amdgcn_mfma_f32_16x16x32_bf16(A1l, B1h, acc11, 0, 0, 0);
        }
    };

    if (SCAN && (blk & 1)) {              // odd blocks: scan first
        scan8();
        __syncthreads();
    }

    stage(lds, 0);
    __syncthreads();
    const int NT = K / 64;                // 8 steps
    for (int st = 0; st < NT; ++st) {
        char* cur = lds + (st & 1) * 32768;
        if (st + 1 < NT) stage(lds + ((st + 1) & 1) * 32768, (st + 1) * 64);
        compute(cur);
        __syncthreads();
    }

    const int orow = hl * 4;
    #pragma unroll
    for (int j = 0; j < 4; ++j) {
        C[(size_t)(bm0 + mq + orow + j) * Nc + bn0 + nq + rl]           = (_Float16)acc00[j];
        C[(size_t)(bm0 + mq + orow + j) * Nc + bn0 + nq + 16 + rl]      = (_Float16)acc01[j];
        C[(size_t)(bm0 + mq + 16 + orow + j) * Nc + bn0 + nq + rl]      = (_Float16)acc10[j];
        C[(size_t)(bm0 + mq + 16 + orow + j) * Nc + bn0 + nq + 16 + rl] = (_Float16)acc11[j];
    }

    // ---- fused s/d epilogue (exact fp32 from acc registers); [row][8] ----
    const int C0 = bn0 + nq + rl, C1 = C0 + 16;
    const float a1c0 = a1v[C0], a1c1 = a1v[C1];
    const float a2c0 = a2v[C0], a2c1 = a2v[C1];
    float ps0[4], ps1[4], pd0[4], pd1[4];
    #pragma unroll
    for (int j = 0; j < 4; ++j) {
        ps0[j] = acc00[j] * a1c0 + acc01[j] * a1c1;
        ps1[j] = acc10[j] * a1c0 + acc11[j] * a1c1;
        pd0[j] = acc00[j] * a2c0 + acc01[j] * a2c1;
        pd1[j] = acc10[j] * a2c0 + acc11[j] * a2c1;
    }
    #pragma unroll
    for (int off = 1; off < 16; off <<= 1) {
        #pragma unroll
        for (int j = 0; j < 4; ++j) {
            ps0[j] += __shfl_xor(ps0[j], off);
            ps1[j] += __shfl_xor(ps1[j], off);
            pd0[j] += __shfl_xor(pd0[j], off);
            pd1[j] += __shfl_xor(pd1[j], off);
        }
    }
    float* eps = (float*)lds;             // [0:64) s rows, [64:128) d rows
    __syncthreads();
    if ((wid & 1) == 0 && rl == 0) {
        #pragma unroll
        for (int j = 0; j < 4; ++j) {
            eps[mq + orow + j]           = ps0[j];
            eps[mq + 16 + orow + j]      = ps1[j];
            eps[64 + mq + orow + j]      = pd0[j];
            eps[64 + mq + 16 + orow + j] = pd1[j];
        }
    }
    __syncthreads();
    if ((wid & 1) == 1 && rl == 0) {
        #pragma unroll
        for (int j = 0; j < 4; ++j) {
            const int t0 = mq + orow + j, t1 = t0 + 16;
            sdst[(size_t)(bm0 + t0) * 8 + bnI] = ps0[j] + eps[t0];
            sdst[(size_t)(bm0 + t1) * 8 + bnI] = ps1[j] + eps[t1];
            ddst[(size_t)(bm0 + t0) * 8 + bnI] = pd0[j] + eps[64 + t0];
            ddst[(size_t)(bm0 + t1) * 8 + bnI] = pd1[j] + eps[64 + t1];
        }
    }

    if (SCAN && !(blk & 1)) {             // even blocks: scan last
        __syncthreads();
        scan8();
    }
}

// ---- attn layer 1 (H=8), 2 rows/block, half-block (128 thr) per row.
// Reads nbrs/deg (written by gemm1x). Logit pass gathers d_t [node][8];
// softmax 16-lane/head; aggregate 4 cols/thread via pipelined f16x4.
__global__ __launch_bounds__(256) void attn8_kernel(
        const _Float16* __restrict__ Wh, const float* __restrict__ s_t,
        const float* __restrict__ d_t,
        const unsigned short* __restrict__ nbr, const int* __restrict__ deg,
        unsigned short* __restrict__ ohi, unsigned short* __restrict__ olo, int N) {
    __shared__ int nb[2][CAP2];
    __shared__ float p[2][8 * PS2];
    __shared__ float lred[2][8];
    const int t = threadIdx.x;
    const int rsel = t >> 7, tid = t & 127;
    const int row = blockIdx.x * 2 + rsel;
    const int M = deg[row];
    for (int j = tid; j < M; j += 128)
        nb[rsel][j] = nbr[(size_t)row * 512 + j];
    __syncthreads();
    // ---- logits ----
    const float4* sp = (const float4*)(s_t + (size_t)row * 8);
    const float4 sA = sp[0], sB = sp[1];
    const float shv[8] = {sA.x, sA.y, sA.z, sA.w, sB.x, sB.y, sB.z, sB.w};
    for (int j = tid; j < M; j += 128) {
        const float4* dp = (const float4*)(d_t + (size_t)nb[rsel][j] * 8);
        const float4 dA = dp[0], dB = dp[1];
        const float dv[8] = {dA.x, dA.y, dA.z, dA.w, dB.x, dB.y, dB.z, dB.w};
        #pragma unroll
        for (int h = 0; h < 8; ++h) {
            float e = shv[h] + dv[h];
            e = e > 0.f ? e : 0.2f * e;   // leaky relu 0.2
            p[rsel][h * PS2 + j] = e;
        }
    }
    __syncthreads();
    // ---- softmax: 16-lane group per head ----
    const int h = tid >> 4, sub = tid & 15;
    float lm = -INFINITY;
    for (int j = sub; j < M; j += 16) lm = fmaxf(lm, p[rsel][h * PS2 + j]);
    #pragma unroll
    for (int off = 8; off; off >>= 1) lm = fmaxf(lm, __shfl_xor(lm, off));
    float ls = 0.f;
    for (int j = sub; j < M; j += 16) {
        float pe = __expf(p[rsel][h * PS2 + j] - lm);
        p[rsel][h * PS2 + j] = pe;
        ls += pe;
    }
    #pragma unroll
    for (int off = 8; off; off >>= 1) ls += __shfl_xor(ls, off);
    if (sub == 0) lred[rsel][h] = ls;
    __syncthreads();
    // ---- aggregate: 4 cols/thread, pipelined 8B loads ----
    const int c = tid * 4;
    const int hc = tid >> 4;              // c/64
    const float inv = 1.f / lred[rsel][hc];
    const _Float16* bp = Wh + c;
    const float* prow = &p[rsel][hc * PS2];
    float a0 = 0.f, a1 = 0.f, a2 = 0.f, a3 = 0.f;
    f16x4 w = *(const f16x4*)(bp + (size_t)nb[rsel][0] * 512);
    float pw = prow[0];
    for (int j = 1; j < M; ++j) {
        const f16x4 wn = *(const f16x4*)(bp + (size_t)nb[rsel][j] * 512);
        const float pn = prow[j];
        a0 += pw * (float)w[0]; a1 += pw * (float)w[1];
        a2 += pw * (float)w[2]; a3 += pw * (float)w[3];
        w = wn; pw = pn;
    }
    a0 += pw * (float)w[0]; a1 += pw * (float)w[1];
    a2 += pw * (float)w[2]; a3 += pw * (float)w[3];
    a0 *= inv; a1 *= inv; a2 *= inv; a3 *= inv;
    a0 = a0 > 0.f ? a0 : __expf(a0) - 1.f;   // ELU (concat heads)
    a1 = a1 > 0.f ? a1 : __expf(a1) - 1.f;
    a2 = a2 > 0.f ? a2 : __expf(a2) - 1.f;
    a3 = a3 > 0.f ? a3 : __expf(a3) - 1.f;
    ushort4 hv, lv;
    split2(a0, hv.x, lv.x); split2(a1, hv.y, lv.y);
    split2(a2, hv.z, lv.z); split2(a3, hv.w, lv.w);
    *(ushort4*)(ohi + (size_t)row * 512 + c) = hv;
    *(ushort4*)(olo + (size_t)row * 512 + c) = lv;
}

// ---- attn layer 2 (H=1), 2 rows/block, half-block per row; s/d [row][8]
// partials; aggregate 4 cols/thread via f16x4, pipelined; f32 out with ELU.
__global__ __launch_bounds__(256) void attn1_kernel(
        const _Float16* __restrict__ Wh, const float* __restrict__ s,
        const float* __restrict__ d, const unsigned short* __restrict__ nbr,
        const int* __restrict__ deg, float* __restrict__ out, int N) {
    __shared__ int nb[2][CAP2];
    __shared__ float p[2][CAP2];
    __shared__ float redm[4], reds[4];
    __shared__ float lred[2];
    const int t = threadIdx.x, lane = t & 63, wv = t >> 6;
    const int rsel = t >> 7, tid = t & 127;
    const int row = blockIdx.x * 2 + rsel;
    const int M = deg[row];
    for (int j = tid; j < M; j += 128)
        nb[rsel][j] = nbr[(size_t)row * 512 + j];
    __syncthreads();
    const float4* sp = (const float4*)(s + (size_t)row * 8);
    float4 s0 = sp[0], s1 = sp[1];
    const float sh = ((s0.x + s0.y) + (s0.z + s0.w)) + ((s1.x + s1.y) + (s1.z + s1.w));
    float lm = -INFINITY;
    for (int j = tid; j < M; j += 128) {
        const float4* dp = (const float4*)(d + (size_t)nb[rsel][j] * 8);
        float4 d0 = dp[0], d1 = dp[1];
        float dv = ((d0.x + d0.y) + (d0.z + d0.w)) + ((d1.x + d1.y) + (d1.z + d1.w));
        float e = sh + dv;
        e = e > 0.f ? e : 0.2f * e;
        p[rsel][j] = e;
        lm = fmaxf(lm, e);
    }
    #pragma unroll
    for (int off = 32; off; off >>= 1) lm = fmaxf(lm, __shfl_xor(lm, off));
    if (lane == 0) redm[wv] = lm;
    __syncthreads();
    lm = fmaxf(redm[rsel * 2], redm[rsel * 2 + 1]);
    float ls = 0.f;
    for (int j = tid; j < M; j += 128) {
        float pe = __expf(p[rsel][j] - lm);
        p[rsel][j] = pe;
        ls += pe;
    }
    #pragma unroll
    for (int off = 32; off; off >>= 1) ls += __shfl_xor(ls, off);
    if (lane == 0) reds[wv] = ls;
    __syncthreads();
    if (tid == 0) lred[rsel] = reds[rsel * 2] + reds[rsel * 2 + 1];
    __syncthreads();
    const int c = tid * 4;
    const float inv = 1.f / lred[rsel];
    const _Float16* bp = Wh + c;
    const float* prow = p[rsel];
    float a0 = 0.f, a1 = 0.f, a2 = 0.f, a3 = 0.f;
    f16x4 w = *(const f16x4*)(bp + (size_t)nb[rsel][0] * 512);
    float pw = prow[0];
    for (int j = 1; j < M; ++j) {
        const f16x4 wn = *(const f16x4*)(bp + (size_t)nb[rsel][j] * 512);
        const float pn = prow[j];
        a0 += pw * (float)w[0]; a1 += pw * (float)w[1];
        a2 += pw * (float)w[2]; a3 += pw * (float)w[3];
        w = wn; pw = pn;
    }
    a0 += pw * (float)w[0]; a1 += pw * (float)w[1];
    a2 += pw * (float)w[2]; a3 += pw * (float)w[3];
    a0 *= inv; a1 *= inv; a2 *= inv; a3 *= inv;
    a0 = a0 > 0.f ? a0 : __expf(a0) - 1.f;
    a1 = a1 > 0.f ? a1 : __expf(a1) - 1.f;
    a2 = a2 > 0.f ? a2 : __expf(a2) - 1.f;
    a3 = a3 > 0.f ? a3 : __expf(a3) - 1.f;
    float4 o; o.x = a0; o.y = a1; o.z = a2; o.w = a3;
    *(float4*)(out + (size_t)row * 512 + c) = o;
}

extern "C" void kernel_launch(void* const* d_in, const int* in_sizes, int n_in,
                              void* d_out, int out_size, void* d_ws, size_t ws_size,
                              hipStream_t stream) {
    const float* x   = (const float*)d_in[0];
    const float* adj = (const float*)d_in[2];
    const float* Ws  = (const float*)d_in[3];
    const float* a1  = (const float*)d_in[4];   // [H][64] flat, c = h*64+k
    const float* a2  = (const float*)d_in[5];
    const float* Wo  = (const float*)d_in[6];
    const float* ao1 = (const float*)d_in[7];   // [512]
    const float* ao2 = (const float*)d_in[8];
    float* out = (float*)d_out;
    const int N = GN;

    char* wsb = (char*)d_ws;
    _Float16* Whh  = (_Float16*)(wsb + 0);            // 4096*512 fp16 = 4 MiB
    _Float16* Whoh = (_Float16*)(wsb + 4194304);      // 4 MiB
    float* s_t   = (float*)(wsb + 8388608);           // 4096*8 f32
    float* d_t   = (float*)(wsb + 8519680);
    float* spart = (float*)(wsb + 8650752);
    float* dpart = (float*)(wsb + 8781824);
    unsigned short* nbrs = (unsigned short*)(wsb + 8912896);   // 4 MiB
    int*            deg  = (int*)(wsb + 13107200);             // 16 KiB
    unsigned short* xhi  = (unsigned short*)(wsb + 13123584);  // 4 MiB
    unsigned short* xlo  = (unsigned short*)(wsb + 17317888);  // 4 MiB
    unsigned short* hch  = (unsigned short*)(wsb + 21512192);  // 4 MiB
    unsigned short* hcl  = (unsigned short*)(wsb + 25706496);  // 4 MiB
    unsigned short* wshi = (unsigned short*)(wsb + 29900800);  // 512 KiB
    unsigned short* wslo = (unsigned short*)(wsb + 30425088);
    unsigned short* wohi = (unsigned short*)(wsb + 30949376);
    unsigned short* wolo = (unsigned short*)(wsb + 31473664);  // end ~32 MiB

    hipLaunchKernelGGL(prep, dim3(2176), dim3(256), 0, stream,
                       Ws, Wo, x, wshi, wslo, wohi, wolo, xhi, xlo);
    hipLaunchKernelGGL((gemm_3t<true>), dim3(512), dim3(256), 0, stream,
                       xhi, xlo, wshi, wslo, a1, a2, Whh, s_t, d_t,
                       adj, nbrs, deg, 4096, 512, 512);
    hipLaunchKernelGGL(attn8_kernel, dim3(2048), dim3(256), 0, stream,
                       Whh, s_t, d_t, nbrs, deg, hch, hcl, N);
    hipLaunchKernelGGL((gemm_3t<false>), dim3(512), dim3(256), 0, stream,
                       hch, hcl, wohi, wolo, ao1, ao2, Whoh, spart, dpart,
                       (const float*)nullptr, (unsigned short*)nullptr,
                       (int*)nullptr, 4096, 512, 512);
    hipLaunchKernelGGL(attn1_kernel, dim3(2048), dim3(256), 0, stream,
                       Whoh, spart, dpart, nbrs, deg, out, N);
}

// Round 18
// 73.243 us; speedup vs baseline: 1.0230x; 1.0230x over previous
//
#include <hip/hip_runtime.h>
#include <hip/hip_bf16.h>
#include <math.h>

// GAT forward, N=4096, F=512, H=8, NH=64.
// Round 18: revert to r16 structure (best, 72.1); add non-temporal loads for
// the single-use adj stream in attn8's scan (protect Whh residency in L2)
// and for prep's x-split reads.

#define GN 4096
#define GF 512
#define CAP2 256
#define PS2 260

typedef __attribute__((ext_vector_type(8))) short bf16x8;
typedef __attribute__((ext_vector_type(4))) float f32x4;
typedef __attribute__((ext_vector_type(4))) float fv4;
typedef __attribute__((ext_vector_type(4))) _Float16 f16x4;

__device__ inline unsigned short f2bf(float f) {
    unsigned u = __float_as_uint(f);
    return (unsigned short)((u + 0x7fffu + ((u >> 16) & 1u)) >> 16);
}
__device__ inline float bf2f(unsigned short h) {
    return __uint_as_float((unsigned)h << 16);
}
__device__ inline void split2(float v, unsigned short& h, unsigned short& l) {
    h = f2bf(v);
    l = f2bf(v - bf2f(h));
}
__device__ inline void gl16(const void* g, void* l) {
    __builtin_amdgcn_global_load_lds((const __attribute__((address_space(1))) unsigned int*)g,
                                     (__attribute__((address_space(3))) unsigned int*)l, 16, 0, 0);
}

// ---- prep: LDS-transposed packs of Ws/Wo + split x. grid = 64+64+2048 ----
__global__ __launch_bounds__(256) void prep(
        const float* __restrict__ Ws, const float* __restrict__ Wo,
        const float* __restrict__ x,
        unsigned short* __restrict__ wshi, unsigned short* __restrict__ wslo,
        unsigned short* __restrict__ wohi, unsigned short* __restrict__ wolo,
        unsigned short* __restrict__ xhi, unsigned short* __restrict__ xlo) {
    __shared__ float T[64][65];
    int b = blockIdx.x;
    const int t = threadIdx.x;
    if (b < 64) {                         // Ws[h][f][k] -> Bt[h*64+k][f], tiled
        const int h = b >> 3, f0 = (b & 7) * 64;
        #pragma unroll
        for (int i = 0; i < 16; ++i) {
            int idx = i * 256 + t;
            int fr = idx >> 6, k = idx & 63;
            T[fr][k] = Ws[h * 32768 + (f0 + fr) * 64 + k];
        }
        __syncthreads();
        #pragma unroll
        for (int i = 0; i < 16; ++i) {
            int idx = i * 256 + t;
            int k = idx >> 6, fr = idx & 63;
            unsigned short hh, ll;
            split2(T[fr][k], hh, ll);
            size_t dst = (size_t)(h * 64 + k) * 512 + f0 + fr;
            wshi[dst] = hh; wslo[dst] = ll;
        }
        return;
    }
    b -= 64;
    if (b < 64) {                         // Wo[f][c] -> Bt[c][f], tiled
        const int c0 = (b >> 3) * 64, f0 = (b & 7) * 64;
        #pragma unroll
        for (int i = 0; i < 16; ++i) {
            int idx = i * 256 + t;
            int fr = idx >> 6, k = idx & 63;
            T[fr][k] = Wo[(size_t)(f0 + fr) * 512 + c0 + k];
        }
        __syncthreads();
        #pragma unroll
        for (int i = 0; i < 16; ++i) {
            int idx = i * 256 + t;
            int k = idx >> 6, fr = idx & 63;
            unsigned short hh, ll;
            split2(T[fr][k], hh, ll);
            size_t dst = (size_t)(c0 + k) * 512 + f0 + fr;
            wohi[dst] = hh; wolo[dst] = ll;
        }
        return;
    }
    b -= 64;
    {                                     // split x -> hi/lo, 2048 blocks
        int i = b * 256 + t;              // [0, 524288)
        fv4 v = __builtin_nontemporal_load((const fv4*)x + i);
        ushort4 h, l;
        split2(v[0], h.x, l.x); split2(v[1], h.y, l.y);
        split2(v[2], h.z, l.z); split2(v[3], h.w, l.w);
        ((ushort4*)xhi)[i] = h;
        ((ushort4*)xlo)[i] = l;
    }
}

// ---- MFMA GEMM: C(fp16) = A@B; A hi/lo [M][K], B hi/lo [Nc][K]; 64x64 tile,
// BK=64, dbuf LDS, 3-term bf16 split, both-sides XOR swizzle, XCD swizzle.
// Epilogue: exact-f32 per-row dots over this block's 64 cols -> s/d[row*8+bnI].
__global__ __launch_bounds__(256) void gemm_3t(
        const unsigned short* __restrict__ Ahi, const unsigned short* __restrict__ Alo,
        const unsigned short* __restrict__ Bhi, const unsigned short* __restrict__ Blo,
        const float* __restrict__ a1v, const float* __restrict__ a2v,
        _Float16* __restrict__ C, float* __restrict__ sdst, float* __restrict__ ddst,
        int M, int K, int Nc) {
    __shared__ char lds[65536];           // 2 buffers x 32KB (Ah|Al|Bh|Bl)
    const int t = threadIdx.x, lane = t & 63, wid = t >> 6;
    const int blk = blockIdx.x;
    const int bmI = (blk & 7) | ((blk >> 6) << 3);   // 0..63
    const int bnI = (blk >> 3) & 7;                  // 0..7
    const int bm0 = bmI * 64, bn0 = bnI * 64;
    const int r0 = t >> 3;
    const int sc8 = (((t & 7) ^ ((t >> 3) & 7)) << 3);   // swizzled chunk, elems
    const size_t aoff = (size_t)(bm0 + r0) * K + sc8;
    const size_t boff = (size_t)(bn0 + r0) * K + sc8;
    const size_t half = (size_t)32 * K;

    auto stage = [&](char* dst, int k0) {
        gl16(Ahi + aoff + k0,        dst + 0 * 4096 + t * 16);
        gl16(Ahi + aoff + half + k0, dst + 1 * 4096 + t * 16);
        gl16(Alo + aoff + k0,        dst + 2 * 4096 + t * 16);
        gl16(Alo + aoff + half + k0, dst + 3 * 4096 + t * 16);
        gl16(Bhi + boff + k0,        dst + 4 * 4096 + t * 16);
        gl16(Bhi + boff + half + k0, dst + 5 * 4096 + t * 16);
        gl16(Blo + boff + k0,        dst + 6 * 4096 + t * 16);
        gl16(Blo + boff + half + k0, dst + 7 * 4096 + t * 16);
    };

    f32x4 acc00 = {0,0,0,0}, acc01 = {0,0,0,0}, acc10 = {0,0,0,0}, acc11 = {0,0,0,0};
    const int mq = (wid >> 1) * 32, nq = (wid & 1) * 32;
    const int rl = lane & 15, hl = lane >> 4;
    const int swz = rl & 7;

    auto compute = [&](const char* Lb) {
        const char* Ah_ = Lb;
        const char* Al_ = Lb + 8192;
        const char* Bh_ = Lb + 16384;
        const char* Bl_ = Lb + 24576;
        #pragma unroll
        for (int s = 0; s < 2; ++s) {
            const int ch = ((s * 4 + hl) ^ swz) * 16;
            const int ra0 = (mq + rl) * 128, ra1 = ra0 + 16 * 128;
            const int rb0 = (nq + rl) * 128, rb1 = rb0 + 16 * 128;
            bf16x8 A0h = *(const bf16x8*)(Ah_ + ra0 + ch);
            bf16x8 A1h = *(const bf16x8*)(Ah_ + ra1 + ch);
            bf16x8 A0l = *(const bf16x8*)(Al_ + ra0 + ch);
            bf16x8 A1l = *(const bf16x8*)(Al_ + ra1 + ch);
            bf16x8 B0h = *(const bf16x8*)(Bh_ + rb0 + ch);
            bf16x8 B1h = *(const bf16x8*)(Bh_ + rb1 + ch);
            bf16x8 B0l = *(const bf16x8*)(Bl_ + rb0 + ch);
            bf16x8 B1l = *(const bf16x8*)(Bl_ + rb1 + ch);
            acc00 = __builtin_amdgcn_mfma_f32_16x16x32_bf16(A0h, B0h, acc00, 0, 0, 0);
            acc01 = __builtin_amdgcn_mfma_f32_16x16x32_bf16(A0h, B1h, acc01, 0, 0, 0);
            acc10 = __builtin_amdgcn_mfma_f32_16x16x32_bf16(A1h, B0h, acc10, 0, 0, 0);
            acc11 = __builtin_amdgcn_mfma_f32_16x16x32_bf16(A1h, B1h, acc11, 0, 0, 0);
            acc00 = __builtin_amdgcn_mfma_f32_16x16x32_bf16(A0h, B0l, acc00, 0, 0, 0);
            acc01 = __builtin_amdgcn_mfma_f32_16x16x32_bf16(A0h, B1l, acc01, 0, 0, 0);
            acc10 = __builtin_amdgcn_mfma_f32_16x16x32_bf16(A1h, B0l, acc10, 0, 0, 0);
            acc11 = __builtin_amdgcn_mfma_f32_16x16x32_bf16(A1h, B1l, acc11, 0, 0, 0);
            acc00 = __builtin_amdgcn_mfma_f32_16x16x32_bf16(A0l, B0h, acc00, 0, 0, 0);
            acc01 = __builtin_amdgcn_mfma_f32_16x16x32_bf16(A0l, B1h, acc01, 0, 0, 0);
            acc10 = __builtin_amdgcn_mfma_f32_16x16x32_bf16(A1l, B0h, acc10, 0, 0, 0);
            acc11 = __builtin_amdgcn_mfma_f32_16x16x32_bf16(A1l, B1h, acc11, 0, 0, 0);
        }
    };

    stage(lds, 0);
    __syncthreads();
    const int NT = K / 64;                // 8 steps
    for (int st = 0; st < NT; ++st) {
        char* cur = lds + (st & 1) * 32768;
        if (st + 1 < NT) stage(lds + ((st + 1) & 1) * 32768, (st + 1) * 64);
        compute(cur);
        __syncthreads();
    }

    const int orow = hl * 4;
    #pragma unroll
    for (int j = 0; j < 4; ++j) {
        C[(size_t)(bm0 + mq + orow + j) * Nc + bn0 + nq + rl]           = (_Float16)acc00[j];
        C[(size_t)(bm0 + mq + orow + j) * Nc + bn0 + nq + 16 + rl]      = (_Float16)acc01[j];
        C[(size_t)(bm0 + mq + 16 + orow + j) * Nc + bn0 + nq + rl]      = (_Float16)acc10[j];
        C[(size_t)(bm0 + mq + 16 + orow + j) * Nc + bn0 + nq + 16 + rl] = (_Float16)acc11[j];
    }

    // ---- fused s/d epilogue (exact fp32 from acc registers); [row][8] ----
    const int C0 = bn0 + nq + rl, C1 = C0 + 16;
    const float a1c0 = a1v[C0], a1c1 = a1v[C1];
    const float a2c0 = a2v[C0], a2c1 = a2v[C1];
    float ps0[4], ps1[4], pd0[4], pd1[4];
    #pragma unroll
    for (int j = 0; j < 4; ++j) {
        ps0[j] = acc00[j] * a1c0 + acc01[j] * a1c1;
        ps1[j] = acc10[j] * a1c0 + acc11[j] * a1c1;
        pd0[j] = acc00[j] * a2c0 + acc01[j] * a2c1;
        pd1[j] = acc10[j] * a2c0 + acc11[j] * a2c1;
    }
    #pragma unroll
    for (int off = 1; off < 16; off <<= 1) {
        #pragma unroll
        for (int j = 0; j < 4; ++j) {
            ps0[j] += __shfl_xor(ps0[j], off);
            ps1[j] += __shfl_xor(ps1[j], off);
            pd0[j] += __shfl_xor(pd0[j], off);
            pd1[j] += __shfl_xor(pd1[j], off);
        }
    }
    float* eps = (float*)lds;             // [0:64) s rows, [64:128) d rows
    if ((wid & 1) == 0 && rl == 0) {
        #pragma unroll
        for (int j = 0; j < 4; ++j) {
            eps[mq + orow + j]           = ps0[j];
            eps[mq + 16 + orow + j]      = ps1[j];
            eps[64 + mq + orow + j]      = pd0[j];
            eps[64 + mq + 16 + orow + j] = pd1[j];
        }
    }
    __syncthreads();
    if ((wid & 1) == 1 && rl == 0) {
        #pragma unroll
        for (int j = 0; j < 4; ++j) {
            const int t0 = mq + orow + j, t1 = t0 + 16;
            sdst[(size_t)(bm0 + t0) * 8 + bnI] = ps0[j] + eps[t0];
            sdst[(size_t)(bm0 + t1) * 8 + bnI] = ps1[j] + eps[t1];
            ddst[(size_t)(bm0 + t0) * 8 + bnI] = pd0[j] + eps[64 + t0];
            ddst[(size_t)(bm0 + t1) * 8 + bnI] = pd1[j] + eps[64 + t1];
        }
    }
}

// ---- attn layer 1 (H=8), 2 rows/block, half-block (128 thr) per row.
// Extraction (non-temporal adj reads) fused with logits; 3 barriers.
// Aggregate: 4 cols/thread via 8B f16x4, software-pipelined.
__global__ __launch_bounds__(256) void attn8_kernel(
        const float* __restrict__ adj,
        const _Float16* __restrict__ Wh, const float* __restrict__ s_t,
        const float* __restrict__ d_t,
        unsigned short* __restrict__ nbr, int* __restrict__ deg,
        unsigned short* __restrict__ ohi, unsigned short* __restrict__ olo, int N) {
    __shared__ int nb[2][CAP2];
    __shared__ float p[2][8 * PS2];
    __shared__ float lred[2][8];
    __shared__ int wtot[4];
    const int t = threadIdx.x, lane = t & 63, wv = t >> 6;
    const int rsel = t >> 7, tid = t & 127;
    const int row = blockIdx.x * 2 + rsel;

    // row s-vector (needed for fused logits)
    const float4* sp = (const float4*)(s_t + (size_t)row * 8);
    const float4 sA = sp[0], sB = sp[1];
    const float shv[8] = {sA.x, sA.y, sA.z, sA.w, sB.x, sB.y, sB.z, sB.w};

    // ---- extraction + fused logits (adj read non-temporally) ----
    const fv4* arow = (const fv4*)(adj + (size_t)row * N);
    unsigned m32 = 0;
    #pragma unroll
    for (int q = 0; q < 8; ++q) {
        fv4 v = __builtin_nontemporal_load(arow + q * 128 + tid);
        if (v[0] > 0.f) m32 |= 1u << (q * 4 + 0);
        if (v[1] > 0.f) m32 |= 1u << (q * 4 + 1);
        if (v[2] > 0.f) m32 |= 1u << (q * 4 + 2);
        if (v[3] > 0.f) m32 |= 1u << (q * 4 + 3);
    }
    const int cnt = __popc(m32);
    int inc = cnt;
    #pragma unroll
    for (int off = 1; off < 64; off <<= 1) {
        int nv = __shfl_up(inc, off);
        if (lane >= off) inc += nv;
    }
    if (lane == 63) wtot[wv] = inc;
    __syncthreads();
    const int base = inc - cnt + ((wv & 1) ? wtot[rsel * 2] : 0);
    const int M = wtot[rsel * 2] + wtot[rsel * 2 + 1];
    if (tid == 0) deg[row] = M;
    {
        unsigned m = m32;
        int k = 0;
        while (m) {
            int b = __ffs(m) - 1;
            m &= m - 1;
            int col = ((b >> 2) << 9) + tid * 4 + (b & 3);
            int slot = base + k;
            nb[rsel][slot] = col;
            nbr[(size_t)row * 512 + slot] = (unsigned short)col;
            const float4* dp = (const float4*)(d_t + (size_t)col * 8);
            const float4 dA = dp[0], dB = dp[1];
            const float dv[8] = {dA.x, dA.y, dA.z, dA.w, dB.x, dB.y, dB.z, dB.w};
            #pragma unroll
            for (int h = 0; h < 8; ++h) {
                float e = shv[h] + dv[h];
                e = e > 0.f ? e : 0.2f * e;   // leaky relu 0.2
                p[rsel][h * PS2 + slot] = e;
            }
            ++k;
        }
    }
    __syncthreads();                      // nb + p ready

    // ---- softmax: 16-lane group per head ----
    const int h = tid >> 4, sub = tid & 15;
    float lm = -INFINITY;
    for (int j = sub; j < M; j += 16) lm = fmaxf(lm, p[rsel][h * PS2 + j]);
    #pragma unroll
    for (int off = 8; off; off >>= 1) lm = fmaxf(lm, __shfl_xor(lm, off));
    float ls = 0.f;
    for (int j = sub; j < M; j += 16) {
        float pe = __expf(p[rsel][h * PS2 + j] - lm);
        p[rsel][h * PS2 + j] = pe;
        ls += pe;
    }
    #pragma unroll
    for (int off = 8; off; off >>= 1) ls += __shfl_xor(ls, off);
    if (sub == 0) lred[rsel][h] = ls;
    __syncthreads();
    // ---- aggregate: 4 cols/thread, pipelined 8B loads ----
    const int c = tid * 4;
    const int hc = tid >> 4;              // c/64
    const float inv = 1.f / lred[rsel][hc];
    const _Float16* bp = Wh + c;
    const float* prow = &p[rsel][hc * PS2];
    float a0 = 0.f, a1 = 0.f, a2 = 0.f, a3 = 0.f;
    f16x4 w = *(const f16x4*)(bp + (size_t)nb[rsel][0] * 512);
    float pw = prow[0];
    for (int j = 1; j < M; ++j) {
        const f16x4 wn = *(const f16x4*)(bp + (size_t)nb[rsel][j] * 512);
        const float pn = prow[j];
        a0 += pw * (float)w[0]; a1 += pw * (float)w[1];
        a2 += pw * (float)w[2]; a3 += pw * (float)w[3];
        w = wn; pw = pn;
    }
    a0 += pw * (float)w[0]; a1 += pw * (float)w[1];
    a2 += pw * (float)w[2]; a3 += pw * (float)w[3];
    a0 *= inv; a1 *= inv; a2 *= inv; a3 *= inv;
    a0 = a0 > 0.f ? a0 : __expf(a0) - 1.f;   // ELU (concat heads)
    a1 = a1 > 0.f ? a1 : __expf(a1) - 1.f;
    a2 = a2 > 0.f ? a2 : __expf(a2) - 1.f;
    a3 = a3 > 0.f ? a3 : __expf(a3) - 1.f;
    ushort4 hv, lv;
    split2(a0, hv.x, lv.x); split2(a1, hv.y, lv.y);
    split2(a2, hv.z, lv.z); split2(a3, hv.w, lv.w);
    *(ushort4*)(ohi + (size_t)row * 512 + c) = hv;
    *(ushort4*)(olo + (size_t)row * 512 + c) = lv;
}

// ---- attn layer 2 (H=1), 2 rows/block, half-block per row; s/d [row][8]
// partials; aggregate 4 cols/thread via f16x4, pipelined; f32 out with ELU.
__global__ __launch_bounds__(256) void attn1_kernel(
        const _Float16* __restrict__ Wh, const float* __restrict__ s,
        const float* __restrict__ d, const unsigned short* __restrict__ nbr,
        const int* __restrict__ deg, float* __restrict__ out, int N) {
    __shared__ int nb[2][CAP2];
    __shared__ float p[2][CAP2];
    __shared__ float redm[4], reds[4];
    __shared__ float lred[2];
    const int t = threadIdx.x, lane = t & 63, wv = t >> 6;
    const int rsel = t >> 7, tid = t & 127;
    const int row = blockIdx.x * 2 + rsel;
    const int M = deg[row];
    for (int j = tid; j < M; j += 128)
        nb[rsel][j] = nbr[(size_t)row * 512 + j];
    __syncthreads();
    const float4* sp = (const float4*)(s + (size_t)row * 8);
    float4 s0 = sp[0], s1 = sp[1];
    const float sh = ((s0.x + s0.y) + (s0.z + s0.w)) + ((s1.x + s1.y) + (s1.z + s1.w));
    float lm = -INFINITY;
    for (int j = tid; j < M; j += 128) {
        const float4* dp = (const float4*)(d + (size_t)nb[rsel][j] * 8);
        float4 d0 = dp[0], d1 = dp[1];
        float dv = ((d0.x + d0.y) + (d0.z + d0.w)) + ((d1.x + d1.y) + (d1.z + d1.w));
        float e = sh + dv;
        e = e > 0.f ? e : 0.2f * e;
        p[rsel][j] = e;
        lm = fmaxf(lm, e);
    }
    #pragma unroll
    for (int off = 32; off; off >>= 1) lm = fmaxf(lm, __shfl_xor(lm, off));
    if (lane == 0) redm[wv] = lm;
    __syncthreads();
    lm = fmaxf(redm[rsel * 2], redm[rsel * 2 + 1]);
    float ls = 0.f;
    for (int j = tid; j < M; j += 128) {
        float pe = __expf(p[rsel][j] - lm);
        p[rsel][j] = pe;
        ls += pe;
    }
    #pragma unroll
    for (int off = 32; off; off >>= 1) ls += __shfl_xor(ls, off);
    if (lane == 0) reds[wv] = ls;
    __syncthreads();
    if (tid == 0) lred[rsel] = reds[rsel * 2] + reds[rsel * 2 + 1];
    __syncthreads();
    const int c = tid * 4;
    const float inv = 1.f / lred[rsel];
    const _Float16* bp = Wh + c;
    const float* prow = p[rsel];
    float a0 = 0.f, a1 = 0.f, a2 = 0.f, a3 = 0.f;
    f16x4 w = *(const f16x4*)(bp + (size_t)nb[rsel][0] * 512);
    float pw = prow[0];
    for (int j = 1; j < M; ++j) {
        const f16x4 wn = *(const f16x4*)(bp + (size_t)nb[rsel][j] * 512);
        const float pn = prow[j];
        a0 += pw * (float)w[0]; a1 += pw * (float)w[1];
        a2 += pw * (float)w[2]; a3 += pw * (float)w[3];
        w = wn; pw = pn;
    }
    a0 += pw * (float)w[0]; a1 += pw * (float)w[1];
    a2 += pw * (float)w[2]; a3 += pw * (float)w[3];
    a0 *= inv; a1 *= inv; a2 *= inv; a3 *= inv;
    a0 = a0 > 0.f ? a0 : __expf(a0) - 1.f;
    a1 = a1 > 0.f ? a1 : __expf(a1) - 1.f;
    a2 = a2 > 0.f ? a2 : __expf(a2) - 1.f;
    a3 = a3 > 0.f ? a3 : __expf(a3) - 1.f;
    float4 o; o.x = a0; o.y = a1; o.z = a2; o.w = a3;
    *(float4*)(out + (size_t)row * 512 + c) = o;
}

extern "C" void kernel_launch(void* const* d_in, const int* in_sizes, int n_in,
                              void* d_out, int out_size, void* d_ws, size_t ws_size,
                              hipStream_t stream) {
    const float* x   = (const float*)d_in[0];
    const float* adj = (const float*)d_in[2];
    const float* Ws  = (const float*)d_in[3];
    const float* a1  = (const float*)d_in[4];   // [H][64] flat, c = h*64+k
    const float* a2  = (const float*)d_in[5];
    const float* Wo  = (const float*)d_in[6];
    const float* ao1 = (const float*)d_in[7];   // [512]
    const float* ao2 = (const float*)d_in[8];
    float* out = (float*)d_out;
    const int N = GN;

    char* wsb = (char*)d_ws;
    _Float16* Whh  = (_Float16*)(wsb + 0);            // 4096*512 fp16 = 4 MiB
    _Float16* Whoh = (_Float16*)(wsb + 4194304);      // 4 MiB
    float* s_t   = (float*)(wsb + 8388608);           // 4096*8 f32
    float* d_t   = (float*)(wsb + 8519680);
    float* spart = (float*)(wsb + 8650752);
    float* dpart = (float*)(wsb + 8781824);
    unsigned short* nbrs = (unsigned short*)(wsb + 8912896);   // 4 MiB
    int*            deg  = (int*)(wsb + 13107200);             // 16 KiB
    unsigned short* xhi  = (unsigned short*)(wsb + 13123584);  // 4 MiB
    unsigned short* xlo  = (unsigned short*)(wsb + 17317888);  // 4 MiB
    unsigned short* hch  = (unsigned short*)(wsb + 21512192);  // 4 MiB
    unsigned short* hcl  = (unsigned short*)(wsb + 25706496);  // 4 MiB
    unsigned short* wshi = (unsigned short*)(wsb + 29900800);  // 512 KiB
    unsigned short* wslo = (unsigned short*)(wsb + 30425088);
    unsigned short* wohi = (unsigned short*)(wsb + 30949376);
    unsigned short* wolo = (unsigned short*)(wsb + 31473664);  // end ~32 MiB

    hipLaunchKernelGGL(prep, dim3(2176), dim3(256), 0, stream,
                       Ws, Wo, x, wshi, wslo, wohi, wolo, xhi, xlo);
    hipLaunchKernelGGL(gemm_3t, dim3(512), dim3(256), 0, stream,
                       xhi, xlo, wshi, wslo, a1, a2, Whh, s_t, d_t, 4096, 512, 512);
    hipLaunchKernelGGL(attn8_kernel, dim3(2048), dim3(256), 0, stream,
                       adj, Whh, s_t, d_t, nbrs, deg, hch, hcl, N);
    hipLaunchKernelGGL(gemm_3t, dim3(512), dim3(256), 0, stream,
                       hch, hcl, wohi, wolo, ao1, ao2, Whoh, spart, dpart, 4096, 512, 512);
    hipLaunchKernelGGL(attn1_kernel, dim3(2048), dim3(256), 0, stream,
                       Whoh, spart, dpart, nbrs, deg, out, N);
}

// Round 19
// 71.995 us; speedup vs baseline: 1.0408x; 1.0173x over previous
//
#include <hip/hip_runtime.h>
#include <hip/hip_bf16.h>
#include <math.h>

// GAT forward, N=4096, F=512, H=8, NH=64.
// Round 19: final lock-in — exact resubmission of the best variant (r16,
// 72.1 us): attn8 extraction+logits fused (3 barriers), pipelined f16x4
// aggregates, 2 rows/block attn, fp16 aggregate operands, XCD-swizzled
// 3-term-bf16 MFMA gemms with fused s/d epilogues, [node][8] s/d layout.

#define GN 4096
#define GF 512
#define CAP2 256
#define PS2 260

typedef __attribute__((ext_vector_type(8))) short bf16x8;
typedef __attribute__((ext_vector_type(4))) float f32x4;
typedef __attribute__((ext_vector_type(2))) _Float16 f16x2;
typedef __attribute__((ext_vector_type(4))) _Float16 f16x4;

__device__ inline unsigned short f2bf(float f) {
    unsigned u = __float_as_uint(f);
    return (unsigned short)((u + 0x7fffu + ((u >> 16) & 1u)) >> 16);
}
__device__ inline float bf2f(unsigned short h) {
    return __uint_as_float((unsigned)h << 16);
}
__device__ inline void split2(float v, unsigned short& h, unsigned short& l) {
    h = f2bf(v);
    l = f2bf(v - bf2f(h));
}
__device__ inline void gl16(const void* g, void* l) {
    __builtin_amdgcn_global_load_lds((const __attribute__((address_space(1))) unsigned int*)g,
                                     (__attribute__((address_space(3))) unsigned int*)l, 16, 0, 0);
}

// ---- prep: LDS-transposed packs of Ws/Wo + split x. grid = 64+64+2048 ----
__global__ __launch_bounds__(256) void prep(
        const float* __restrict__ Ws, const float* __restrict__ Wo,
        const float* __restrict__ x,
        unsigned short* __restrict__ wshi, unsigned short* __restrict__ wslo,
        unsigned short* __restrict__ wohi, unsigned short* __restrict__ wolo,
        unsigned short* __restrict__ xhi, unsigned short* __restrict__ xlo) {
    __shared__ float T[64][65];
    int b = blockIdx.x;
    const int t = threadIdx.x;
    if (b < 64) {                         // Ws[h][f][k] -> Bt[h*64+k][f], tiled
        const int h = b >> 3, f0 = (b & 7) * 64;
        #pragma unroll
        for (int i = 0; i < 16; ++i) {
            int idx = i * 256 + t;
            int fr = idx >> 6, k = idx & 63;
            T[fr][k] = Ws[h * 32768 + (f0 + fr) * 64 + k];
        }
        __syncthreads();
        #pragma unroll
        for (int i = 0; i < 16; ++i) {
            int idx = i * 256 + t;
            int k = idx >> 6, fr = idx & 63;
            unsigned short hh, ll;
            split2(T[fr][k], hh, ll);
            size_t dst = (size_t)(h * 64 + k) * 512 + f0 + fr;
            wshi[dst] = hh; wslo[dst] = ll;
        }
        return;
    }
    b -= 64;
    if (b < 64) {                         // Wo[f][c] -> Bt[c][f], tiled
        const int c0 = (b >> 3) * 64, f0 = (b & 7) * 64;
        #pragma unroll
        for (int i = 0; i < 16; ++i) {
            int idx = i * 256 + t;
            int fr = idx >> 6, k = idx & 63;
            T[fr][k] = Wo[(size_t)(f0 + fr) * 512 + c0 + k];
        }
        __syncthreads();
        #pragma unroll
        for (int i = 0; i < 16; ++i) {
            int idx = i * 256 + t;
            int k = idx >> 6, fr = idx & 63;
            unsigned short hh, ll;
            split2(T[fr][k], hh, ll);
            size_t dst = (size_t)(c0 + k) * 512 + f0 + fr;
            wohi[dst] = hh; wolo[dst] = ll;
        }
        return;
    }
    b -= 64;
    {                                     // split x -> hi/lo, 2048 blocks
        int i = b * 256 + t;              // [0, 524288)
        float4 v = ((const float4*)x)[i];
        ushort4 h, l;
        split2(v.x, h.x, l.x); split2(v.y, h.y, l.y);
        split2(v.z, h.z, l.z); split2(v.w, h.w, l.w);
        ((ushort4*)xhi)[i] = h;
        ((ushort4*)xlo)[i] = l;
    }
}

// ---- MFMA GEMM: C(fp16) = A@B; A hi/lo [M][K], B hi/lo [Nc][K]; 64x64 tile,
// BK=64, dbuf LDS, 3-term bf16 split, both-sides XOR swizzle, XCD swizzle.
// Epilogue: exact-f32 per-row dots over this block's 64 cols -> s/d[row*8+bnI].
__global__ __launch_bounds__(256) void gemm_3t(
        const unsigned short* __restrict__ Ahi, const unsigned short* __restrict__ Alo,
        const unsigned short* __restrict__ Bhi, const unsigned short* __restrict__ Blo,
        const float* __restrict__ a1v, const float* __restrict__ a2v,
        _Float16* __restrict__ C, float* __restrict__ sdst, float* __restrict__ ddst,
        int M, int K, int Nc) {
    __shared__ char lds[65536];           // 2 buffers x 32KB (Ah|Al|Bh|Bl)
    const int t = threadIdx.x, lane = t & 63, wid = t >> 6;
    const int blk = blockIdx.x;
    const int bmI = (blk & 7) | ((blk >> 6) << 3);   // 0..63
    const int bnI = (blk >> 3) & 7;                  // 0..7
    const int bm0 = bmI * 64, bn0 = bnI * 64;
    const int r0 = t >> 3;
    const int sc8 = (((t & 7) ^ ((t >> 3) & 7)) << 3);   // swizzled chunk, elems
    const size_t aoff = (size_t)(bm0 + r0) * K + sc8;
    const size_t boff = (size_t)(bn0 + r0) * K + sc8;
    const size_t half = (size_t)32 * K;

    auto stage = [&](char* dst, int k0) {
        gl16(Ahi + aoff + k0,        dst + 0 * 4096 + t * 16);
        gl16(Ahi + aoff + half + k0, dst + 1 * 4096 + t * 16);
        gl16(Alo + aoff + k0,        dst + 2 * 4096 + t * 16);
        gl16(Alo + aoff + half + k0, dst + 3 * 4096 + t * 16);
        gl16(Bhi + boff + k0,        dst + 4 * 4096 + t * 16);
        gl16(Bhi + boff + half + k0, dst + 5 * 4096 + t * 16);
        gl16(Blo + boff + k0,        dst + 6 * 4096 + t * 16);
        gl16(Blo + boff + half + k0, dst + 7 * 4096 + t * 16);
    };

    f32x4 acc00 = {0,0,0,0}, acc01 = {0,0,0,0}, acc10 = {0,0,0,0}, acc11 = {0,0,0,0};
    const int mq = (wid >> 1) * 32, nq = (wid & 1) * 32;
    const int rl = lane & 15, hl = lane >> 4;
    const int swz = rl & 7;

    auto compute = [&](const char* Lb) {
        const char* Ah_ = Lb;
        const char* Al_ = Lb + 8192;
        const char* Bh_ = Lb + 16384;
        const char* Bl_ = Lb + 24576;
        #pragma unroll
        for (int s = 0; s < 2; ++s) {
            const int ch = ((s * 4 + hl) ^ swz) * 16;
            const int ra0 = (mq + rl) * 128, ra1 = ra0 + 16 * 128;
            const int rb0 = (nq + rl) * 128, rb1 = rb0 + 16 * 128;
            bf16x8 A0h = *(const bf16x8*)(Ah_ + ra0 + ch);
            bf16x8 A1h = *(const bf16x8*)(Ah_ + ra1 + ch);
            bf16x8 A0l = *(const bf16x8*)(Al_ + ra0 + ch);
            bf16x8 A1l = *(const bf16x8*)(Al_ + ra1 + ch);
            bf16x8 B0h = *(const bf16x8*)(Bh_ + rb0 + ch);
            bf16x8 B1h = *(const bf16x8*)(Bh_ + rb1 + ch);
            bf16x8 B0l = *(const bf16x8*)(Bl_ + rb0 + ch);
            bf16x8 B1l = *(const bf16x8*)(Bl_ + rb1 + ch);
            acc00 = __builtin_amdgcn_mfma_f32_16x16x32_bf16(A0h, B0h, acc00, 0, 0, 0);
            acc01 = __builtin_amdgcn_mfma_f32_16x16x32_bf16(A0h, B1h, acc01, 0, 0, 0);
            acc10 = __builtin_amdgcn_mfma_f32_16x16x32_bf16(A1h, B0h, acc10, 0, 0, 0);
            acc11 = __builtin_amdgcn_mfma_f32_16x16x32_bf16(A1h, B1h, acc11, 0, 0, 0);
            acc00 = __builtin_amdgcn_mfma_f32_16x16x32_bf16(A0h, B0l, acc00, 0, 0, 0);
            acc01 = __builtin_amdgcn_mfma_f32_16x16x32_bf16(A0h, B1l, acc01, 0, 0, 0);
            acc10 = __builtin_amdgcn_mfma_f32_16x16x32_bf16(A1h, B0l, acc10, 0, 0, 0);
            acc11 = __builtin_amdgcn_mfma_f32_16x16x32_bf16(A1h, B1l, acc11, 0, 0, 0);
            acc00 = __builtin_amdgcn_mfma_f32_16x16x32_bf16(A0l, B0h, acc00, 0, 0, 0);
            acc01 = __builtin_amdgcn_mfma_f32_16x16x32_bf16(A0l, B1h, acc01, 0, 0, 0);
            acc10 = __builtin_amdgcn_mfma_f32_16x16x32_bf16(A1l, B0h, acc10, 0, 0, 0);
            acc11 = __builtin_amdgcn_mfma_f32_16x16x32_bf16(A1l, B1h, acc11, 0, 0, 0);
        }
    };

    stage(lds, 0);
    __syncthreads();
    const int NT = K / 64;                // 8 steps
    for (int st = 0; st < NT; ++st) {
        char* cur = lds + (st & 1) * 32768;
        if (st + 1 < NT) stage(lds + ((st + 1) & 1) * 32768, (st + 1) * 64);
        compute(cur);
        __syncthreads();
    }

    const int orow = hl * 4;
    #pragma unroll
    for (int j = 0; j < 4; ++j) {
        C[(size_t)(bm0 + mq + orow + j) * Nc + bn0 + nq + rl]           = (_Float16)acc00[j];
        C[(size_t)(bm0 + mq + orow + j) * Nc + bn0 + nq + 16 + rl]      = (_Float16)acc01[j];
        C[(size_t)(bm0 + mq + 16 + orow + j) * Nc + bn0 + nq + rl]      = (_Float16)acc10[j];
        C[(size_t)(bm0 + mq + 16 + orow + j) * Nc + bn0 + nq + 16 + rl] = (_Float16)acc11[j];
    }

    // ---- fused s/d epilogue (exact fp32 from acc registers); [row][8] ----
    const int C0 = bn0 + nq + rl, C1 = C0 + 16;
    const float a1c0 = a1v[C0], a1c1 = a1v[C1];
    const float a2c0 = a2v[C0], a2c1 = a2v[C1];
    float ps0[4], ps1[4], pd0[4], pd1[4];
    #pragma unroll
    for (int j = 0; j < 4; ++j) {
        ps0[j] = acc00[j] * a1c0 + acc01[j] * a1c1;
        ps1[j] = acc10[j] * a1c0 + acc11[j] * a1c1;
        pd0[j] = acc00[j] * a2c0 + acc01[j] * a2c1;
        pd1[j] = acc10[j] * a2c0 + acc11[j] * a2c1;
    }
    #pragma unroll
    for (int off = 1; off < 16; off <<= 1) {
        #pragma unroll
        for (int j = 0; j < 4; ++j) {
            ps0[j] += __shfl_xor(ps0[j], off);
            ps1[j] += __shfl_xor(ps1[j], off);
            pd0[j] += __shfl_xor(pd0[j], off);
            pd1[j] += __shfl_xor(pd1[j], off);
        }
    }
    float* eps = (float*)lds;             // [0:64) s rows, [64:128) d rows
    if ((wid & 1) == 0 && rl == 0) {
        #pragma unroll
        for (int j = 0; j < 4; ++j) {
            eps[mq + orow + j]           = ps0[j];
            eps[mq + 16 + orow + j]      = ps1[j];
            eps[64 + mq + orow + j]      = pd0[j];
            eps[64 + mq + 16 + orow + j] = pd1[j];
        }
    }
    __syncthreads();
    if ((wid & 1) == 1 && rl == 0) {
        #pragma unroll
        for (int j = 0; j < 4; ++j) {
            const int t0 = mq + orow + j, t1 = t0 + 16;
            sdst[(size_t)(bm0 + t0) * 8 + bnI] = ps0[j] + eps[t0];
            sdst[(size_t)(bm0 + t1) * 8 + bnI] = ps1[j] + eps[t1];
            ddst[(size_t)(bm0 + t0) * 8 + bnI] = pd0[j] + eps[64 + t0];
            ddst[(size_t)(bm0 + t1) * 8 + bnI] = pd1[j] + eps[64 + t1];
        }
    }
}

// ---- attn layer 1 (H=8), 2 rows/block, half-block (128 thr) per row.
// Extraction fused with logits: on neighbor discovery, gather d_t[col][0..8)
// and write all 8 leaky-relu logits (no separate logit pass). 3 barriers.
// Aggregate: 4 cols/thread via 8B f16x4, software-pipelined.
__global__ __launch_bounds__(256) void attn8_kernel(
        const float* __restrict__ adj,
        const _Float16* __restrict__ Wh, const float* __restrict__ s_t,
        const float* __restrict__ d_t,
        unsigned short* __restrict__ nbr, int* __restrict__ deg,
        unsigned short* __restrict__ ohi, unsigned short* __restrict__ olo, int N) {
    __shared__ int nb[2][CAP2];
    __shared__ float p[2][8 * PS2];
    __shared__ float lred[2][8];
    __shared__ int wtot[4];
    const int t = threadIdx.x, lane = t & 63, wv = t >> 6;
    const int rsel = t >> 7, tid = t & 127;
    const int row = blockIdx.x * 2 + rsel;

    // row s-vector (needed for fused logits)
    const float4* sp = (const float4*)(s_t + (size_t)row * 8);
    const float4 sA = sp[0], sB = sp[1];
    const float shv[8] = {sA.x, sA.y, sA.z, sA.w, sB.x, sB.y, sB.z, sB.w};

    // ---- extraction + fused logits ----
    const float4* arow = (const float4*)(adj + (size_t)row * N);
    unsigned m32 = 0;
    #pragma unroll
    for (int q = 0; q < 8; ++q) {
        float4 v = arow[q * 128 + tid];   // coalesced per wave
        if (v.x > 0.f) m32 |= 1u << (q * 4 + 0);
        if (v.y > 0.f) m32 |= 1u << (q * 4 + 1);
        if (v.z > 0.f) m32 |= 1u << (q * 4 + 2);
        if (v.w > 0.f) m32 |= 1u << (q * 4 + 3);
    }
    const int cnt = __popc(m32);
    int inc = cnt;
    #pragma unroll
    for (int off = 1; off < 64; off <<= 1) {
        int nv = __shfl_up(inc, off);
        if (lane >= off) inc += nv;
    }
    if (lane == 63) wtot[wv] = inc;
    __syncthreads();
    const int base = inc - cnt + ((wv & 1) ? wtot[rsel * 2] : 0);
    const int M = wtot[rsel * 2] + wtot[rsel * 2 + 1];
    if (tid == 0) deg[row] = M;
    {
        unsigned m = m32;
        int k = 0;
        while (m) {
            int b = __ffs(m) - 1;
            m &= m - 1;
            int col = ((b >> 2) << 9) + tid * 4 + (b & 3);
            int slot = base + k;
            nb[rsel][slot] = col;
            nbr[(size_t)row * 512 + slot] = (unsigned short)col;
            const float4* dp = (const float4*)(d_t + (size_t)col * 8);
            const float4 dA = dp[0], dB = dp[1];
            const float dv[8] = {dA.x, dA.y, dA.z, dA.w, dB.x, dB.y, dB.z, dB.w};
            #pragma unroll
            for (int h = 0; h < 8; ++h) {
                float e = shv[h] + dv[h];
                e = e > 0.f ? e : 0.2f * e;   // leaky relu 0.2
                p[rsel][h * PS2 + slot] = e;
            }
            ++k;
        }
    }
    __syncthreads();                      // nb + p ready

    // ---- softmax: 16-lane group per head ----
    const int h = tid >> 4, sub = tid & 15;
    float lm = -INFINITY;
    for (int j = sub; j < M; j += 16) lm = fmaxf(lm, p[rsel][h * PS2 + j]);
    #pragma unroll
    for (int off = 8; off; off >>= 1) lm = fmaxf(lm, __shfl_xor(lm, off));
    float ls = 0.f;
    for (int j = sub; j < M; j += 16) {
        float pe = __expf(p[rsel][h * PS2 + j] - lm);
        p[rsel][h * PS2 + j] = pe;
        ls += pe;
    }
    #pragma unroll
    for (int off = 8; off; off >>= 1) ls += __shfl_xor(ls, off);
    if (sub == 0) lred[rsel][h] = ls;
    __syncthreads();
    // ---- aggregate: 4 cols/thread, pipelined 8B loads ----
    const int c = tid * 4;
    const int hc = tid >> 4;              // c/64
    const float inv = 1.f / lred[rsel][hc];
    const _Float16* bp = Wh + c;
    const float* prow = &p[rsel][hc * PS2];
    float a0 = 0.f, a1 = 0.f, a2 = 0.f, a3 = 0.f;
    f16x4 w = *(const f16x4*)(bp + (size_t)nb[rsel][0] * 512);
    float pw = prow[0];
    for (int j = 1; j < M; ++j) {
        const f16x4 wn = *(const f16x4*)(bp + (size_t)nb[rsel][j] * 512);
        const float pn = prow[j];
        a0 += pw * (float)w[0]; a1 += pw * (float)w[1];
        a2 += pw * (float)w[2]; a3 += pw * (float)w[3];
        w = wn; pw = pn;
    }
    a0 += pw * (float)w[0]; a1 += pw * (float)w[1];
    a2 += pw * (float)w[2]; a3 += pw * (float)w[3];
    a0 *= inv; a1 *= inv; a2 *= inv; a3 *= inv;
    a0 = a0 > 0.f ? a0 : __expf(a0) - 1.f;   // ELU (concat heads)
    a1 = a1 > 0.f ? a1 : __expf(a1) - 1.f;
    a2 = a2 > 0.f ? a2 : __expf(a2) - 1.f;
    a3 = a3 > 0.f ? a3 : __expf(a3) - 1.f;
    ushort4 hv, lv;
    split2(a0, hv.x, lv.x); split2(a1, hv.y, lv.y);
    split2(a2, hv.z, lv.z); split2(a3, hv.w, lv.w);
    *(ushort4*)(ohi + (size_t)row * 512 + c) = hv;
    *(ushort4*)(olo + (size_t)row * 512 + c) = lv;
}

// ---- attn layer 2 (H=1), 2 rows/block, half-block per row; s/d [row][8]
// partials; aggregate 4 cols/thread via f16x4, pipelined; f32 out with ELU.
__global__ __launch_bounds__(256) void attn1_kernel(
        const _Float16* __restrict__ Wh, const float* __restrict__ s,
        const float* __restrict__ d, const unsigned short* __restrict__ nbr,
        const int* __restrict__ deg, float* __restrict__ out, int N) {
    __shared__ int nb[2][CAP2];
    __shared__ float p[2][CAP2];
    __shared__ float redm[4], reds[4];
    __shared__ float lred[2];
    const int t = threadIdx.x, lane = t & 63, wv = t >> 6;
    const int rsel = t >> 7, tid = t & 127;
    const int row = blockIdx.x * 2 + rsel;
    const int M = deg[row];
    for (int j = tid; j < M; j += 128)
        nb[rsel][j] = nbr[(size_t)row * 512 + j];
    __syncthreads();
    const float4* sp = (const float4*)(s + (size_t)row * 8);
    float4 s0 = sp[0], s1 = sp[1];
    const float sh = ((s0.x + s0.y) + (s0.z + s0.w)) + ((s1.x + s1.y) + (s1.z + s1.w));
    float lm = -INFINITY;
    for (int j = tid; j < M; j += 128) {
        const float4* dp = (const float4*)(d + (size_t)nb[rsel][j] * 8);
        float4 d0 = dp[0], d1 = dp[1];
        float dv = ((d0.x + d0.y) + (d0.z + d0.w)) + ((d1.x + d1.y) + (d1.z + d1.w));
        float e = sh + dv;
        e = e > 0.f ? e : 0.2f * e;
        p[rsel][j] = e;
        lm = fmaxf(lm, e);
    }
    #pragma unroll
    for (int off = 32; off; off >>= 1) lm = fmaxf(lm, __shfl_xor(lm, off));
    if (lane == 0) redm[wv] = lm;
    __syncthreads();
    lm = fmaxf(redm[rsel * 2], redm[rsel * 2 + 1]);
    float ls = 0.f;
    for (int j = tid; j < M; j += 128) {
        float pe = __expf(p[rsel][j] - lm);
        p[rsel][j] = pe;
        ls += pe;
    }
    #pragma unroll
    for (int off = 32; off; off >>= 1) ls += __shfl_xor(ls, off);
    if (lane == 0) reds[wv] = ls;
    __syncthreads();
    if (tid == 0) lred[rsel] = reds[rsel * 2] + reds[rsel * 2 + 1];
    __syncthreads();
    const int c = tid * 4;
    const float inv = 1.f / lred[rsel];
    const _Float16* bp = Wh + c;
    const float* prow = p[rsel];
    float a0 = 0.f, a1 = 0.f, a2 = 0.f, a3 = 0.f;
    f16x4 w = *(const f16x4*)(bp + (size_t)nb[rsel][0] * 512);
    float pw = prow[0];
    for (int j = 1; j < M; ++j) {
        const f16x4 wn = *(const f16x4*)(bp + (size_t)nb[rsel][j] * 512);
        const float pn = prow[j];
        a0 += pw * (float)w[0]; a1 += pw * (float)w[1];
        a2 += pw * (float)w[2]; a3 += pw * (float)w[3];
        w = wn; pw = pn;
    }
    a0 += pw * (float)w[0]; a1 += pw * (float)w[1];
    a2 += pw * (float)w[2]; a3 += pw * (float)w[3];
    a0 *= inv; a1 *= inv; a2 *= inv; a3 *= inv;
    a0 = a0 > 0.f ? a0 : __expf(a0) - 1.f;
    a1 = a1 > 0.f ? a1 : __expf(a1) - 1.f;
    a2 = a2 > 0.f ? a2 : __expf(a2) - 1.f;
    a3 = a3 > 0.f ? a3 : __expf(a3) - 1.f;
    float4 o; o.x = a0; o.y = a1; o.z = a2; o.w = a3;
    *(float4*)(out + (size_t)row * 512 + c) = o;
}

extern "C" void kernel_launch(void* const* d_in, const int* in_sizes, int n_in,
                              void* d_out, int out_size, void* d_ws, size_t ws_size,
                              hipStream_t stream) {
    const float* x   = (const float*)d_in[0];
    const float* adj = (const float*)d_in[2];
    const float* Ws  = (const float*)d_in[3];
    const float* a1  = (const float*)d_in[4];   // [H][64] flat, c = h*64+k
    const float* a2  = (const float*)d_in[5];
    const float* Wo  = (const float*)d_in[6];
    const float* ao1 = (const float*)d_in[7];   // [512]
    const float* ao2 = (const float*)d_in[8];
    float* out = (float*)d_out;
    const int N = GN;

    char* wsb = (char*)d_ws;
    _Float16* Whh  = (_Float16*)(wsb + 0);            // 4096*512 fp16 = 4 MiB
    _Float16* Whoh = (_Float16*)(wsb + 4194304);      // 4 MiB
    float* s_t   = (float*)(wsb + 8388608);           // 4096*8 f32
    float* d_t   = (float*)(wsb + 8519680);
    float* spart = (float*)(wsb + 8650752);
    float* dpart = (float*)(wsb + 8781824);
    unsigned short* nbrs = (unsigned short*)(wsb + 8912896);   // 4 MiB
    int*            deg  = (int*)(wsb + 13107200);             // 16 KiB
    unsigned short* xhi  = (unsigned short*)(wsb + 13123584);  // 4 MiB
    unsigned short* xlo  = (unsigned short*)(wsb + 17317888);  // 4 MiB
    unsigned short* hch  = (unsigned short*)(wsb + 21512192);  // 4 MiB
    unsigned short* hcl  = (unsigned short*)(wsb + 25706496);  // 4 MiB
    unsigned short* wshi = (unsigned short*)(wsb + 29900800);  // 512 KiB
    unsigned short* wslo = (unsigned short*)(wsb + 30425088);
    unsigned short* wohi = (unsigned short*)(wsb + 30949376);
    unsigned short* wolo = (unsigned short*)(wsb + 31473664);  // end ~32 MiB

    hipLaunchKernelGGL(prep, dim3(2176), dim3(256), 0, stream,
                       Ws, Wo, x, wshi, wslo, wohi, wolo, xhi, xlo);
    hipLaunchKernelGGL(gemm_3t, dim3(512), dim3(256), 0, stream,
                       xhi, xlo, wshi, wslo, a1, a2, Whh, s_t, d_t, 4096, 512, 512);
    hipLaunchKernelGGL(attn8_kernel, dim3(2048), dim3(256), 0, stream,
                       adj, Whh, s_t, d_t, nbrs, deg, hch, hcl, N);
    hipLaunchKernelGGL(gemm_3t, dim3(512), dim3(256), 0, stream,
                       hch, hcl, wohi, wolo, ao1, ao2, Whoh, spart, dpart, 4096, 512, 512);
    hipLaunchKernelGGL(attn1_kernel, dim3(2048), dim3(256), 0, stream,
                       Whoh, spart, dpart, nbrs, deg, out, N);
}